// Round 7
// baseline (575.580 us; speedup 1.0000x reference)
//
#include <hip/hip_runtime.h>
#include <hip/hip_bf16.h>

typedef __hip_bfloat16 bf16;
typedef __attribute__((ext_vector_type(8))) short v8s;   // 8 bf16 raw (4 VGPRs)
typedef __attribute__((ext_vector_type(4))) short v4s;   // 4 bf16 raw (8 B)
typedef __attribute__((ext_vector_type(4))) float v4f;   // MFMA C/D frag

#define MFMA(a, b, c) __builtin_amdgcn_mfma_f32_16x16x32_bf16((a), (b), (c), 0, 0, 0)

static constexpr int BB = 2, SEQ = 4096, HIDN = 2048, NH = 16, NKV = 4, HD = 128;
static constexpr float SCALE = 0.08838834764831845f;  // 128^-0.5
static constexpr float NEGV = -1e9f;

__device__ __forceinline__ bf16 f2b(float x) { return __float2bfloat16(x); }

// async global->LDS, 16B per lane. ldst wave-uniform; lane i lands at ldst+i*16.
__device__ __forceinline__ void glds16(const bf16* g, bf16* l) {
  __builtin_amdgcn_global_load_lds(
      (const __attribute__((address_space(1))) unsigned int*)g,
      (__attribute__((address_space(3))) unsigned int*)l, 16, 0, 0);
}

// ---------------------------------------------------------------- fp32 -> bf16
// vectorized: float4 in, 4x bf16 (8 B) out per thread. n must be %4 == 0.
__global__ void convert_k(const float* __restrict__ X, bf16* __restrict__ Y, long n) {
  long i4 = ((long)blockIdx.x * 256 + threadIdx.x) * 4;
  if (i4 >= n) return;
  v4f x = *(const v4f*)(X + i4);
  bf16 t[4];
#pragma unroll
  for (int j = 0; j < 4; j++) t[j] = f2b(x[j]);
  *(v4s*)(Y + i4) = *(const v4s*)t;
}

// ---------------------------------------------------------------- transpose+cast
// 64x64 LDS tile; coalesced f32 reads (256 B/wave) and bf16 writes (128 B/wave).
// Wt[n*K+k] = W[k*N+n]. Requires K,N multiples of 64.  (round-3 validated)
__global__ __launch_bounds__(256) void transpose_k(const float* __restrict__ W,
                                                   bf16* __restrict__ Wt,
                                                   int K, int N) {
  __shared__ bf16 tile[64][65];
  const int tx = threadIdx.x & 63, ty = threadIdx.x >> 6;  // 64 x 4
  const int k0 = blockIdx.y << 6, n0 = blockIdx.x << 6;
#pragma unroll
  for (int rr = 0; rr < 64; rr += 4)
    tile[tx][rr + ty] = f2b(W[(long)(k0 + rr + ty) * N + n0 + tx]);
  __syncthreads();
#pragma unroll
  for (int rr = 0; rr < 64; rr += 4)
    Wt[(long)(n0 + rr + ty) * K + k0 + tx] = tile[rr + ty][tx];
}

// ---------------------------------------------------------------- GEMM (B^T)
// XCD-aware bijective block swizzle (T1), round-5 validated (total fell 35 us).
// Inner loop unchanged (replay-validated).
template <int MODE, typename OT>
__global__ __launch_bounds__(256) void gemm128(const bf16* __restrict__ A,
                                               const bf16* __restrict__ Bt,
                                               OT* __restrict__ C,
                                               int M, int N, int K) {
  __shared__ __align__(16) bf16 As[2][128 * 32];
  __shared__ __align__(16) bf16 Bs[2][128 * 32];

  const int tid = threadIdx.x;
  const int lane = tid & 63, wv = tid >> 6;
  const int wr = wv >> 1, wc = wv & 1;
  const int l15 = lane & 15, quad = lane >> 4;

  const int nwg = gridDim.x * gridDim.y;
  int bid = blockIdx.y * gridDim.x + blockIdx.x;
  bid = (bid & 7) * (nwg >> 3) + (bid >> 3);
  const int m0 = (bid / gridDim.x) * 128, n0 = (bid % gridDim.x) * 128;

  const bf16* aSrc = A + (long)(m0 + (tid >> 2)) * K + (tid & 3) * 8;
  const bf16* bSrc = Bt + (long)(n0 + (tid >> 2)) * K + (tid & 3) * 8;
  const long rowStride = (long)64 * K;

  int aoff[4], boff[4];
#pragma unroll
  for (int t = 0; t < 4; t++) {
    aoff[t] = (wr * 64 + t * 16 + l15) * 32 + quad * 8;
    boff[t] = (wc * 64 + t * 16 + l15) * 32 + quad * 8;
  }

  v4f acc[4][4];
#pragma unroll
  for (int i = 0; i < 4; i++)
#pragma unroll
    for (int j = 0; j < 4; j++) acc[i][j] = {0.f, 0.f, 0.f, 0.f};

  const int nIter = K >> 5;
  for (int it = 0; it < nIter; ++it) {
    const int kc = it << 5;
    const int bsel = it & 1;
    bf16* aD = As[bsel] + wv * 512;
    bf16* bD = Bs[bsel] + wv * 512;
    glds16(aSrc + kc, aD);
    glds16(aSrc + rowStride + kc, aD + 2048);
    glds16(bSrc + kc, bD);
    glds16(bSrc + rowStride + kc, bD + 2048);
    asm volatile("s_waitcnt vmcnt(0)" ::: "memory");
    __syncthreads();

    const bf16* Ab = As[bsel];
    const bf16* Bb = Bs[bsel];
    v8s af[4], bfv[4];
#pragma unroll
    for (int t = 0; t < 4; t++) {
      af[t] = *(const v8s*)(Ab + aoff[t]);
      bfv[t] = *(const v8s*)(Bb + boff[t]);
    }
#pragma unroll
    for (int i = 0; i < 4; i++)
#pragma unroll
      for (int j = 0; j < 4; j++) acc[i][j] = MFMA(af[i], bfv[j], acc[i][j]);
  }

#pragma unroll
  for (int i = 0; i < 4; i++)
#pragma unroll
    for (int j = 0; j < 4; j++)
#pragma unroll
      for (int r = 0; r < 4; r++) {
        int m = m0 + wr * 64 + i * 16 + quad * 4 + r;
        int n = n0 + wc * 64 + j * 16 + l15;
        long addr;
        if (MODE == 0) {
          addr = (long)m * N + n;
        } else {
          int bb = m >> 12, s = m & (SEQ - 1);
          int hh = n >> 7, d = n & (HD - 1);
          if (MODE == 1)      addr = ((long)(bb * NH + hh) * SEQ + s) * HD + d;
          else if (MODE == 2) addr = ((long)(bb * NKV + hh) * SEQ + s) * HD + d;
          else                addr = ((long)(bb * NKV + hh) * HD + d) * SEQ + s;
        }
        float v = acc[i][j][r];
        if constexpr (sizeof(OT) == 2) C[addr] = f2b(v);
        else                           C[addr] = v;
      }
}

// ---------------------------------------------------------------- RoPE (in place)
__global__ void rope_k(bf16* __restrict__ X, const float* __restrict__ cs,
                       const float* __restrict__ sn, int nheads) {
  int idx = blockIdx.x * 256 + threadIdx.x;
  int d = idx & 63;
  int row = idx >> 6;
  int s = row & (SEQ - 1);
  int bh = row >> 12;
  int b = bh / nheads;
  long xo = (long)row * HD;
  long co = ((long)b * SEQ + s) * HD;
  float x1 = __bfloat162float(X[xo + d]), x2 = __bfloat162float(X[xo + d + 64]);
  float c1 = cs[co + d], c2 = cs[co + d + 64];
  float s1 = sn[co + d], s2 = sn[co + d + 64];
  X[xo + d] = f2b(x1 * c1 - x2 * s1);
  X[xo + d + 64] = f2b(x2 * c2 + x1 * s2);
}

// ---------------------------------------------------------------- attention
// Round-7 change: 16-wave blocks (1024 thr), grid (64 qblk, 4 kv, 2 b) = 512
// blocks. Round-6 counters: MfmaUtil 10%, occupancy 21.6%, HBM 13.6% -- pure
// latency exposure: 2048 blocks x 2/CU = 32 iteration-slots of ~9700 cyc each
// against ~600 cyc of work, and each K/V block was re-staged by 32 different
// blocks (512 MB DMA for 16.8 MB unique K/V). Merging the 4 j-slices into one
// block: waves/CU 8->16 (4/SIMD TLP), iteration-slots 32->16, staging DMA /4.
// Per-wave compute code identical to round-6 (validated); only the staging
// work split changes (16 waves: 1 K-call + 1 V-call each instead of 4+4).
// Wave (j = wv>>2, h = kv*4 + (wv&3)). LDS: 32K K-dbuf + 32K V-dbuf + 36K pb
// = 100 KB -> 1 block/CU; 512 blocks = exactly 2 generations, no tail.
__global__ __launch_bounds__(1024) void attn_k(const bf16* __restrict__ Q,
                                               const bf16* __restrict__ K,
                                               const bf16* __restrict__ V,
                                               const float* __restrict__ msk,
                                               bf16* __restrict__ ctx) {
  const int i = blockIdx.x;                       // qblock
  const int kv = blockIdx.y, b = blockIdx.z;
  const int lane = threadIdx.x & 63, wv = threadIdx.x >> 6;  // 16 waves
  const int j = wv >> 2;                          // 16-row slice 0..3
  const int h = kv * 4 + (wv & 3);                // this wave's q-head
  const int l15 = lane & 15, quad = lane >> 4;

  __shared__ __align__(16) bf16 kbuf[2][8192];   // K block: 64 tok x 128 d
  __shared__ __align__(16) bf16 vbuf[2][8192];   // V block: 128 d x 64 tok
  __shared__ __align__(16) bf16 pb[16][16][72];  // per-wave P transpose

  // key-block table: kb[0..3] local (kb[3]==i self), kb[4..7] strided global
  int kb[8];
  bool kval[8];
#pragma unroll
  for (int w = 0; w < 4; w++) { kb[w] = i - 3 + w; kval[w] = (kb[w] >= 0); }
  {
    int st = i - 32; if (st < 0) st = 0;
    int n = i - st;
    int cnt = (n + 3) >> 2;
#pragma unroll
    for (int t = 0; t < 4; t++) {
      int jj = cnt + t - 4;
      kval[4 + t] = (jj >= 0);
      kb[4 + t] = (jj >= 0) ? (st + 4 * jj) : 0;
    }
  }
  int kbc[8];
#pragma unroll
  for (int t = 0; t < 8; t++) kbc[t] = kb[t] < 0 ? 0 : kb[t];  // clamped for staging

  // Q fragments: this wave's 16 q-rows
  const bf16* qp = Q + ((long)(b * NH + h) * SEQ + i * 64 + j * 16 + l15) * HD + quad * 8;
  v8s qf[4];
#pragma unroll
  for (int kk = 0; kk < 4; kk++) qf[kk] = *(const v8s*)(qp + kk * 32);

  // staging lane geometry (K): 4 rows/call (64 rows / 16 waves), 16B granules
  const int klr = lane >> 4, kgp = lane & 15;
  // staging lane geometry (V): 8 rows/call (128 rows / 16 waves)
  const int vlr = lane >> 3, vgp = lane & 7;

  const bf16* gk = K + (long)(b * NKV + kv) * SEQ * HD;
  const bf16* gv = V + (long)(b * NKV + kv) * HD * SEQ;

  // stage K block blk: LDS[row][g'] = K[row][g' ^ (row&15)]; wave wv stages
  // token rows wv*4 .. wv*4+3 in ONE glds16 (64 lanes x 16B = 4 rows x 256B)
  auto stageK = [&](int blk, bf16* dst) {
    const bf16* kbase = gk + (long)blk * 64 * HD;
    int tl = wv * 4 + klr;                        // token row 0..63
    int g = kgp ^ (tl & 15);
    glds16(kbase + (long)tl * HD + g * 8, dst + (wv * 4) * 128);
  };
  // stage V block blk: LDS[row][g'] = V[row][g' ^ (row&7)]; wave wv stages
  // d rows wv*8 .. wv*8+7 in ONE glds16 (64 lanes x 16B = 8 rows x 128B)
  auto stageV = [&](int blk, bf16* dst) {
    const bf16* vbase = gv + (long)blk * 64;      // token offset within d-rows
    int row = wv * 8 + vlr;                       // d row 0..127
    int g = vgp ^ (row & 7);
    glds16(vbase + (long)row * SEQ + g * 8, dst + (wv * 8) * 64);
  };

  float rsum[4] = {0.f, 0.f, 0.f, 0.f};
  v4f oacc[8] = {{0.f, 0.f, 0.f, 0.f}, {0.f, 0.f, 0.f, 0.f}, {0.f, 0.f, 0.f, 0.f},
                 {0.f, 0.f, 0.f, 0.f}, {0.f, 0.f, 0.f, 0.f}, {0.f, 0.f, 0.f, 0.f},
                 {0.f, 0.f, 0.f, 0.f}, {0.f, 0.f, 0.f, 0.f}};

  stageK(kbc[0], kbuf[0]);
  stageV(kbc[0], vbuf[0]);
  asm volatile("s_waitcnt vmcnt(0)" ::: "memory");
  __syncthreads();

#pragma unroll
  for (int it = 0; it < 8; ++it) {
    const int bsel = it & 1;
    if (it < 7) {
      stageK(kbc[it + 1], kbuf[bsel ^ 1]);
      stageV(kbc[it + 1], vbuf[bsel ^ 1]);
    }

    // ---- QK^T -> exp -> pb, fused per t (exp of tile t overlaps MFMA of t+1)
    const bf16* Kb = kbuf[bsel];
    __builtin_amdgcn_s_setprio(1);
#pragma unroll
    for (int t = 0; t < 4; t++) {
      v4f acc = {0.f, 0.f, 0.f, 0.f};
#pragma unroll
      for (int kk = 0; kk < 4; kk++) {
        int off = (t * 16 + l15) * 128 + (((kk * 4 + quad) ^ l15) * 8);
        acc = MFMA(qf[kk], *(const v8s*)(Kb + off), acc);
      }
      int tokc = kbc[it] * 64 + t * 16 + l15;
      float madd = kval[it] ? (1.0f - msk[b * SEQ + tokc]) * NEGV : NEGV;
#pragma unroll
      for (int r = 0; r < 4; r++) {
        float x = acc[r] * SCALE + madd;
        if (it == 3) {  // self block: causal within block
          int kpp = t * 16 + l15;
          int qpp = j * 16 + quad * 4 + r;
          if (kpp > qpp) x += NEGV;
        }
        float e = __expf(x);   // masked -> exp(~-1e9) = 0 exactly
        rsum[r] += e;
        pb[wv][quad * 4 + r][t * 16 + l15] = f2b(e);
      }
    }
    __builtin_amdgcn_s_setprio(0);

    // ---- PV accumulate (pb write->read ordered by lgkmcnt within the wave)
    const bf16* Vb = vbuf[bsel];
    __builtin_amdgcn_s_setprio(1);
#pragma unroll
    for (int hf = 0; hf < 2; hf++) {
      v8s af = *(const v8s*)&pb[wv][l15][hf * 32 + quad * 8];
#pragma unroll
      for (int nt = 0; nt < 8; nt++) {
        int off = (nt * 16 + l15) * 64 + (((hf * 4 + quad) ^ (l15 & 7)) * 8);
        oacc[nt] = MFMA(af, *(const v8s*)(Vb + off), oacc[nt]);
      }
    }
    __builtin_amdgcn_s_setprio(0);
    // single per-iteration barrier; drains the it+1 DMA (vmcnt(0) before
    // s_barrier) and separates this iteration's LDS reads from it+1 writes
    __syncthreads();
  }

  // ---- final sum reduce across the 16 column-lanes (once, outside the loop)
#pragma unroll
  for (int m = 1; m <= 8; m <<= 1)
#pragma unroll
    for (int r = 0; r < 4; r++) rsum[r] += __shfl_xor(rsum[r], m, 64);

  // ---- normalize + write ctx[b][s][h*128+d]
  const int tokw = i * 64 + j * 16 + quad * 4;
#pragma unroll
  for (int nt = 0; nt < 8; nt++)
#pragma unroll
    for (int r = 0; r < 4; r++) {
      float v = oacc[nt][r] / rsum[r];
      long addr = ((long)b * SEQ + tokw + r) * (NH * HD) + h * HD + nt * 16 + l15;
      ctx[addr] = f2b(v);
    }
}

// ---------------------------------------------------------------- launch
extern "C" void kernel_launch(void* const* d_in, const int* in_sizes, int n_in,
                              void* d_out, int out_size, void* d_ws, size_t ws_size,
                              hipStream_t stream) {
  const float* hs  = (const float*)d_in[0];
  const float* cs  = (const float*)d_in[1];
  const float* sn  = (const float*)d_in[2];
  const float* msk = (const float*)d_in[3];
  const float* Wq  = (const float*)d_in[4];
  const float* Wk  = (const float*)d_in[5];
  const float* Wv  = (const float*)d_in[6];
  const float* Wo  = (const float*)d_in[7];
  float* out = (float*)d_out;

  char* w = (char*)d_ws;
  bf16* hsb = (bf16*)w; w += (size_t)BB * SEQ * HIDN * 2;       // 33.5 MB
  bf16* Wqt = (bf16*)w; w += (size_t)2048 * 2048 * 2;           //  8.4 MB
  bf16* Wkt = (bf16*)w; w += (size_t)512 * 2048 * 2;            //  2.1 MB
  bf16* Wvt = (bf16*)w; w += (size_t)512 * 2048 * 2;            //  2.1 MB
  bf16* Wot = (bf16*)w; w += (size_t)2048 * 2048 * 2;           //  8.4 MB
  bf16* Qr  = (bf16*)w; w += (size_t)BB * NH * SEQ * HD * 2;    // 33.5 MB
  bf16* Kr  = (bf16*)w; w += (size_t)BB * NKV * SEQ * HD * 2;   //  8.4 MB
  bf16* Vt  = (bf16*)w; w += (size_t)BB * NKV * HD * SEQ * 2;   //  8.4 MB
  bf16* ctx = hsb;  // hsb dead after V-proj; stream-ordered reuse
  // total ws use: ~105 MB

  long nhs = (long)BB * SEQ * HIDN;
  convert_k<<<(int)(nhs / 4 / 256), 256, 0, stream>>>(hs, hsb, nhs);

  transpose_k<<<dim3(2048 / 64, 2048 / 64), 256, 0, stream>>>(Wq, Wqt, 2048, 2048);
  transpose_k<<<dim3(512 / 64, 2048 / 64), 256, 0, stream>>>(Wk, Wkt, 2048, 512);
  transpose_k<<<dim3(512 / 64, 2048 / 64), 256, 0, stream>>>(Wv, Wvt, 2048, 512);
  transpose_k<<<dim3(2048 / 64, 2048 / 64), 256, 0, stream>>>(Wo, Wot, 2048, 2048);

  gemm128<1, bf16><<<dim3(2048 / 128, 8192 / 128), 256, 0, stream>>>(hsb, Wqt, Qr, 8192, 2048, 2048);
  gemm128<2, bf16><<<dim3(512 / 128, 8192 / 128), 256, 0, stream>>>(hsb, Wkt, Kr, 8192, 512, 2048);
  gemm128<3, bf16><<<dim3(512 / 128, 8192 / 128), 256, 0, stream>>>(hsb, Wvt, Vt, 8192, 512, 2048);

  rope_k<<<(BB * NH * SEQ * 64) / 256, 256, 0, stream>>>(Qr, cs, sn, NH);
  rope_k<<<(BB * NKV * SEQ * 64) / 256, 256, 0, stream>>>(Kr, cs, sn, NKV);

  attn_k<<<dim3(64, 4, 2), 1024, 0, stream>>>(Qr, Kr, Vt, msk, ctx);

  gemm128<0, float><<<dim3(2048 / 128, 8192 / 128), 256, 0, stream>>>(ctx, Wot, out, 8192, 2048, 2048);
}

// Round 8
// 537.604 us; speedup vs baseline: 1.0706x; 1.0706x over previous
//
#include <hip/hip_runtime.h>
#include <hip/hip_bf16.h>

typedef __hip_bfloat16 bf16;
typedef __attribute__((ext_vector_type(8))) short v8s;   // 8 bf16 raw (4 VGPRs)
typedef __attribute__((ext_vector_type(4))) short v4s;   // 4 bf16 raw (8 B)
typedef __attribute__((ext_vector_type(4))) float v4f;   // MFMA C/D frag

#define MFMA(a, b, c) __builtin_amdgcn_mfma_f32_16x16x32_bf16((a), (b), (c), 0, 0, 0)

static constexpr int BB = 2, SEQ = 4096, HIDN = 2048, NH = 16, NKV = 4, HD = 128;
static constexpr float SCALE = 0.08838834764831845f;  // 128^-0.5
static constexpr float NEGV = -1e9f;

__device__ __forceinline__ bf16 f2b(float x) { return __float2bfloat16(x); }

// async global->LDS, 16B per lane. ldst wave-uniform; lane i lands at ldst+i*16.
__device__ __forceinline__ void glds16(const bf16* g, bf16* l) {
  __builtin_amdgcn_global_load_lds(
      (const __attribute__((address_space(1))) unsigned int*)g,
      (__attribute__((address_space(3))) unsigned int*)l, 16, 0, 0);
}

// ---------------------------------------------------------------- fp32 -> bf16
// vectorized: float4 in, 4x bf16 (8 B) out per thread. n must be %4 == 0.
__global__ void convert_k(const float* __restrict__ X, bf16* __restrict__ Y, long n) {
  long i4 = ((long)blockIdx.x * 256 + threadIdx.x) * 4;
  if (i4 >= n) return;
  v4f x = *(const v4f*)(X + i4);
  bf16 t[4];
#pragma unroll
  for (int j = 0; j < 4; j++) t[j] = f2b(x[j]);
  *(v4s*)(Y + i4) = *(const v4s*)t;
}

// ---------------------------------------------------------------- transpose+cast
// 64x64 LDS tile; coalesced f32 reads (256 B/wave) and bf16 writes (128 B/wave).
// Wt[n*K+k] = W[k*N+n]. Requires K,N multiples of 64.  (round-3 validated)
__global__ __launch_bounds__(256) void transpose_k(const float* __restrict__ W,
                                                   bf16* __restrict__ Wt,
                                                   int K, int N) {
  __shared__ bf16 tile[64][65];
  const int tx = threadIdx.x & 63, ty = threadIdx.x >> 6;  // 64 x 4
  const int k0 = blockIdx.y << 6, n0 = blockIdx.x << 6;
#pragma unroll
  for (int rr = 0; rr < 64; rr += 4)
    tile[tx][rr + ty] = f2b(W[(long)(k0 + rr + ty) * N + n0 + tx]);
  __syncthreads();
#pragma unroll
  for (int rr = 0; rr < 64; rr += 4)
    Wt[(long)(n0 + rr + ty) * K + k0 + tx] = tile[rr + ty][tx];
}

// ---------------------------------------------------------------- GEMM (B^T)
// Round-8 change: 2-deep pipeline (T3 minimum), same reorder validated on attn
// in rounds 1/4-7. Round-7 counters: big GEMMs 113 us, MfmaUtil 25%, HBM 13%,
// ~1060 cyc/iter vs ~230 cyc of work -- the old stage->drain->compute order
// exposed full HBM latency every iteration. Now: prologue stages tile 0; each
// iteration issues stage(it+1) into the other LDS buffer BEFORE compute(it);
// the vmcnt(0)+barrier sits after compute where the DMA has mostly landed.
// Hazards: compute(it) reads [bsel] (landed at prior barrier); stage(it+1)
// writes [bsel^1] whose readers (compute(it-1)) are barrier-separated.
// XCD swizzle (T1) kept (round-5 validated). Epilogue unchanged.
template <int MODE, typename OT>
__global__ __launch_bounds__(256) void gemm128(const bf16* __restrict__ A,
                                               const bf16* __restrict__ Bt,
                                               OT* __restrict__ C,
                                               int M, int N, int K) {
  __shared__ __align__(16) bf16 As[2][128 * 32];
  __shared__ __align__(16) bf16 Bs[2][128 * 32];

  const int tid = threadIdx.x;
  const int lane = tid & 63, wv = tid >> 6;
  const int wr = wv >> 1, wc = wv & 1;
  const int l15 = lane & 15, quad = lane >> 4;

  const int nwg = gridDim.x * gridDim.y;
  int bid = blockIdx.y * gridDim.x + blockIdx.x;
  bid = (bid & 7) * (nwg >> 3) + (bid >> 3);
  const int m0 = (bid / gridDim.x) * 128, n0 = (bid % gridDim.x) * 128;

  const bf16* aSrc = A + (long)(m0 + (tid >> 2)) * K + (tid & 3) * 8;
  const bf16* bSrc = Bt + (long)(n0 + (tid >> 2)) * K + (tid & 3) * 8;
  const long rowStride = (long)64 * K;

  int aoff[4], boff[4];
#pragma unroll
  for (int t = 0; t < 4; t++) {
    aoff[t] = (wr * 64 + t * 16 + l15) * 32 + quad * 8;
    boff[t] = (wc * 64 + t * 16 + l15) * 32 + quad * 8;
  }

  v4f acc[4][4];
#pragma unroll
  for (int i = 0; i < 4; i++)
#pragma unroll
    for (int j = 0; j < 4; j++) acc[i][j] = {0.f, 0.f, 0.f, 0.f};

  const int nIter = K >> 5;

  // prologue: stage tile 0
  {
    bf16* aD = As[0] + wv * 512;
    bf16* bD = Bs[0] + wv * 512;
    glds16(aSrc, aD);
    glds16(aSrc + rowStride, aD + 2048);
    glds16(bSrc, bD);
    glds16(bSrc + rowStride, bD + 2048);
    asm volatile("s_waitcnt vmcnt(0)" ::: "memory");
    __syncthreads();
  }

  for (int it = 0; it < nIter; ++it) {
    const int bsel = it & 1;
    if (it + 1 < nIter) {
      const int kc = (it + 1) << 5;
      bf16* aD = As[bsel ^ 1] + wv * 512;
      bf16* bD = Bs[bsel ^ 1] + wv * 512;
      glds16(aSrc + kc, aD);
      glds16(aSrc + rowStride + kc, aD + 2048);
      glds16(bSrc + kc, bD);
      glds16(bSrc + rowStride + kc, bD + 2048);
    }

    const bf16* Ab = As[bsel];
    const bf16* Bb = Bs[bsel];
    v8s af[4], bfv[4];
#pragma unroll
    for (int t = 0; t < 4; t++) {
      af[t] = *(const v8s*)(Ab + aoff[t]);
      bfv[t] = *(const v8s*)(Bb + boff[t]);
    }
#pragma unroll
    for (int i = 0; i < 4; i++)
#pragma unroll
      for (int j = 0; j < 4; j++) acc[i][j] = MFMA(af[i], bfv[j], acc[i][j]);

    // drain next-tile DMA (mostly landed during MFMA) + cross-wave sync
    asm volatile("s_waitcnt vmcnt(0)" ::: "memory");
    __syncthreads();
  }

#pragma unroll
  for (int i = 0; i < 4; i++)
#pragma unroll
    for (int j = 0; j < 4; j++)
#pragma unroll
      for (int r = 0; r < 4; r++) {
        int m = m0 + wr * 64 + i * 16 + quad * 4 + r;
        int n = n0 + wc * 64 + j * 16 + l15;
        long addr;
        if (MODE == 0) {
          addr = (long)m * N + n;
        } else {
          int bb = m >> 12, s = m & (SEQ - 1);
          int hh = n >> 7, d = n & (HD - 1);
          if (MODE == 1)      addr = ((long)(bb * NH + hh) * SEQ + s) * HD + d;
          else if (MODE == 2) addr = ((long)(bb * NKV + hh) * SEQ + s) * HD + d;
          else                addr = ((long)(bb * NKV + hh) * HD + d) * SEQ + s;
        }
        float v = acc[i][j][r];
        if constexpr (sizeof(OT) == 2) C[addr] = f2b(v);
        else                           C[addr] = v;
      }
}

// ---------------------------------------------------------------- RoPE (in place)
__global__ void rope_k(bf16* __restrict__ X, const float* __restrict__ cs,
                       const float* __restrict__ sn, int nheads) {
  int idx = blockIdx.x * 256 + threadIdx.x;
  int d = idx & 63;
  int row = idx >> 6;
  int s = row & (SEQ - 1);
  int bh = row >> 12;
  int b = bh / nheads;
  long xo = (long)row * HD;
  long co = ((long)b * SEQ + s) * HD;
  float x1 = __bfloat162float(X[xo + d]), x2 = __bfloat162float(X[xo + d + 64]);
  float c1 = cs[co + d], c2 = cs[co + d + 64];
  float s1 = sn[co + d], s2 = sn[co + d + 64];
  X[xo + d] = f2b(x1 * c1 - x2 * s1);
  X[xo + d + 64] = f2b(x2 * c2 + x1 * s2);
}

// ---------------------------------------------------------------- attention
// Round-7 structure (bit-identical): 16-wave blocks (1024 thr), grid
// (64 qblk, 4 kv, 2 b) = 512 blocks. No-max softmax (round-6 validated).
// 2-deep stage(it+1)||compute(it) pipeline, one barrier per iteration.
// LDS: 32K K-dbuf + 32K V-dbuf + 36K pb = 100 KB -> 1 block/CU.
__global__ __launch_bounds__(1024) void attn_k(const bf16* __restrict__ Q,
                                               const bf16* __restrict__ K,
                                               const bf16* __restrict__ V,
                                               const float* __restrict__ msk,
                                               bf16* __restrict__ ctx) {
  const int i = blockIdx.x;                       // qblock
  const int kv = blockIdx.y, b = blockIdx.z;
  const int lane = threadIdx.x & 63, wv = threadIdx.x >> 6;  // 16 waves
  const int j = wv >> 2;                          // 16-row slice 0..3
  const int h = kv * 4 + (wv & 3);                // this wave's q-head
  const int l15 = lane & 15, quad = lane >> 4;

  __shared__ __align__(16) bf16 kbuf[2][8192];   // K block: 64 tok x 128 d
  __shared__ __align__(16) bf16 vbuf[2][8192];   // V block: 128 d x 64 tok
  __shared__ __align__(16) bf16 pb[16][16][72];  // per-wave P transpose

  // key-block table: kb[0..3] local (kb[3]==i self), kb[4..7] strided global
  int kb[8];
  bool kval[8];
#pragma unroll
  for (int w = 0; w < 4; w++) { kb[w] = i - 3 + w; kval[w] = (kb[w] >= 0); }
  {
    int st = i - 32; if (st < 0) st = 0;
    int n = i - st;
    int cnt = (n + 3) >> 2;
#pragma unroll
    for (int t = 0; t < 4; t++) {
      int jj = cnt + t - 4;
      kval[4 + t] = (jj >= 0);
      kb[4 + t] = (jj >= 0) ? (st + 4 * jj) : 0;
    }
  }
  int kbc[8];
#pragma unroll
  for (int t = 0; t < 8; t++) kbc[t] = kb[t] < 0 ? 0 : kb[t];  // clamped for staging

  // Q fragments: this wave's 16 q-rows
  const bf16* qp = Q + ((long)(b * NH + h) * SEQ + i * 64 + j * 16 + l15) * HD + quad * 8;
  v8s qf[4];
#pragma unroll
  for (int kk = 0; kk < 4; kk++) qf[kk] = *(const v8s*)(qp + kk * 32);

  // staging lane geometry (K): 4 rows/call (64 rows / 16 waves), 16B granules
  const int klr = lane >> 4, kgp = lane & 15;
  // staging lane geometry (V): 8 rows/call (128 rows / 16 waves)
  const int vlr = lane >> 3, vgp = lane & 7;

  const bf16* gk = K + (long)(b * NKV + kv) * SEQ * HD;
  const bf16* gv = V + (long)(b * NKV + kv) * HD * SEQ;

  // stage K block blk: LDS[row][g'] = K[row][g' ^ (row&15)]; wave wv stages
  // token rows wv*4 .. wv*4+3 in ONE glds16 (64 lanes x 16B = 4 rows x 256B)
  auto stageK = [&](int blk, bf16* dst) {
    const bf16* kbase = gk + (long)blk * 64 * HD;
    int tl = wv * 4 + klr;                        // token row 0..63
    int g = kgp ^ (tl & 15);
    glds16(kbase + (long)tl * HD + g * 8, dst + (wv * 4) * 128);
  };
  // stage V block blk: LDS[row][g'] = V[row][g' ^ (row&7)]; wave wv stages
  // d rows wv*8 .. wv*8+7 in ONE glds16 (64 lanes x 16B = 8 rows x 128B)
  auto stageV = [&](int blk, bf16* dst) {
    const bf16* vbase = gv + (long)blk * 64;      // token offset within d-rows
    int row = wv * 8 + vlr;                       // d row 0..127
    int g = vgp ^ (row & 7);
    glds16(vbase + (long)row * SEQ + g * 8, dst + (wv * 8) * 64);
  };

  float rsum[4] = {0.f, 0.f, 0.f, 0.f};
  v4f oacc[8] = {{0.f, 0.f, 0.f, 0.f}, {0.f, 0.f, 0.f, 0.f}, {0.f, 0.f, 0.f, 0.f},
                 {0.f, 0.f, 0.f, 0.f}, {0.f, 0.f, 0.f, 0.f}, {0.f, 0.f, 0.f, 0.f},
                 {0.f, 0.f, 0.f, 0.f}, {0.f, 0.f, 0.f, 0.f}};

  stageK(kbc[0], kbuf[0]);
  stageV(kbc[0], vbuf[0]);
  asm volatile("s_waitcnt vmcnt(0)" ::: "memory");
  __syncthreads();

#pragma unroll
  for (int it = 0; it < 8; ++it) {
    const int bsel = it & 1;
    if (it < 7) {
      stageK(kbc[it + 1], kbuf[bsel ^ 1]);
      stageV(kbc[it + 1], vbuf[bsel ^ 1]);
    }

    // ---- QK^T -> exp -> pb, fused per t (exp of tile t overlaps MFMA of t+1)
    const bf16* Kb = kbuf[bsel];
    __builtin_amdgcn_s_setprio(1);
#pragma unroll
    for (int t = 0; t < 4; t++) {
      v4f acc = {0.f, 0.f, 0.f, 0.f};
#pragma unroll
      for (int kk = 0; kk < 4; kk++) {
        int off = (t * 16 + l15) * 128 + (((kk * 4 + quad) ^ l15) * 8);
        acc = MFMA(qf[kk], *(const v8s*)(Kb + off), acc);
      }
      int tokc = kbc[it] * 64 + t * 16 + l15;
      float madd = kval[it] ? (1.0f - msk[b * SEQ + tokc]) * NEGV : NEGV;
#pragma unroll
      for (int r = 0; r < 4; r++) {
        float x = acc[r] * SCALE + madd;
        if (it == 3) {  // self block: causal within block
          int kpp = t * 16 + l15;
          int qpp = j * 16 + quad * 4 + r;
          if (kpp > qpp) x += NEGV;
        }
        float e = __expf(x);   // masked -> exp(~-1e9) = 0 exactly
        rsum[r] += e;
        pb[wv][quad * 4 + r][t * 16 + l15] = f2b(e);
      }
    }
    __builtin_amdgcn_s_setprio(0);

    // ---- PV accumulate (pb write->read ordered by lgkmcnt within the wave)
    const bf16* Vb = vbuf[bsel];
    __builtin_amdgcn_s_setprio(1);
#pragma unroll
    for (int hf = 0; hf < 2; hf++) {
      v8s af = *(const v8s*)&pb[wv][l15][hf * 32 + quad * 8];
#pragma unroll
      for (int nt = 0; nt < 8; nt++) {
        int off = (nt * 16 + l15) * 64 + (((hf * 4 + quad) ^ (l15 & 7)) * 8);
        oacc[nt] = MFMA(af, *(const v8s*)(Vb + off), oacc[nt]);
      }
    }
    __builtin_amdgcn_s_setprio(0);
    // single per-iteration barrier; drains the it+1 DMA (vmcnt(0) before
    // s_barrier) and separates this iteration's LDS reads from it+1 writes
    __syncthreads();
  }

  // ---- final sum reduce across the 16 column-lanes (once, outside the loop)
#pragma unroll
  for (int m = 1; m <= 8; m <<= 1)
#pragma unroll
    for (int r = 0; r < 4; r++) rsum[r] += __shfl_xor(rsum[r], m, 64);

  // ---- normalize + write ctx[b][s][h*128+d]
  const int tokw = i * 64 + j * 16 + quad * 4;
#pragma unroll
  for (int nt = 0; nt < 8; nt++)
#pragma unroll
    for (int r = 0; r < 4; r++) {
      float v = oacc[nt][r] / rsum[r];
      long addr = ((long)b * SEQ + tokw + r) * (NH * HD) + h * HD + nt * 16 + l15;
      ctx[addr] = f2b(v);
    }
}

// ---------------------------------------------------------------- launch
extern "C" void kernel_launch(void* const* d_in, const int* in_sizes, int n_in,
                              void* d_out, int out_size, void* d_ws, size_t ws_size,
                              hipStream_t stream) {
  const float* hs  = (const float*)d_in[0];
  const float* cs  = (const float*)d_in[1];
  const float* sn  = (const float*)d_in[2];
  const float* msk = (const float*)d_in[3];
  const float* Wq  = (const float*)d_in[4];
  const float* Wk  = (const float*)d_in[5];
  const float* Wv  = (const float*)d_in[6];
  const float* Wo  = (const float*)d_in[7];
  float* out = (float*)d_out;

  char* w = (char*)d_ws;
  bf16* hsb = (bf16*)w; w += (size_t)BB * SEQ * HIDN * 2;       // 33.5 MB
  bf16* Wqt = (bf16*)w; w += (size_t)2048 * 2048 * 2;           //  8.4 MB
  bf16* Wkt = (bf16*)w; w += (size_t)512 * 2048 * 2;            //  2.1 MB
  bf16* Wvt = (bf16*)w; w += (size_t)512 * 2048 * 2;            //  2.1 MB
  bf16* Wot = (bf16*)w; w += (size_t)2048 * 2048 * 2;           //  8.4 MB
  bf16* Qr  = (bf16*)w; w += (size_t)BB * NH * SEQ * HD * 2;    // 33.5 MB
  bf16* Kr  = (bf16*)w; w += (size_t)BB * NKV * SEQ * HD * 2;   //  8.4 MB
  bf16* Vt  = (bf16*)w; w += (size_t)BB * NKV * HD * SEQ * 2;   //  8.4 MB
  bf16* ctx = hsb;  // hsb dead after V-proj; stream-ordered reuse
  // total ws use: ~105 MB

  long nhs = (long)BB * SEQ * HIDN;
  convert_k<<<(int)(nhs / 4 / 256), 256, 0, stream>>>(hs, hsb, nhs);

  transpose_k<<<dim3(2048 / 64, 2048 / 64), 256, 0, stream>>>(Wq, Wqt, 2048, 2048);
  transpose_k<<<dim3(512 / 64, 2048 / 64), 256, 0, stream>>>(Wk, Wkt, 2048, 512);
  transpose_k<<<dim3(512 / 64, 2048 / 64), 256, 0, stream>>>(Wv, Wvt, 2048, 512);
  transpose_k<<<dim3(2048 / 64, 2048 / 64), 256, 0, stream>>>(Wo, Wot, 2048, 2048);

  gemm128<1, bf16><<<dim3(2048 / 128, 8192 / 128), 256, 0, stream>>>(hsb, Wqt, Qr, 8192, 2048, 2048);
  gemm128<2, bf16><<<dim3(512 / 128, 8192 / 128), 256, 0, stream>>>(hsb, Wkt, Kr, 8192, 512, 2048);
  gemm128<3, bf16><<<dim3(512 / 128, 8192 / 128), 256, 0, stream>>>(hsb, Wvt, Vt, 8192, 512, 2048);

  rope_k<<<(BB * NH * SEQ * 64) / 256, 256, 0, stream>>>(Qr, cs, sn, NH);
  rope_k<<<(BB * NKV * SEQ * 64) / 256, 256, 0, stream>>>(Kr, cs, sn, NKV);

  attn_k<<<dim3(64, 4, 2), 1024, 0, stream>>>(Qr, Kr, Vt, msk, ctx);

  gemm128<0, float><<<dim3(2048 / 128, 8192 / 128), 256, 0, stream>>>(ctx, Wot, out, 8192, 2048, 2048);
}

// Round 9
// 533.877 us; speedup vs baseline: 1.0781x; 1.0070x over previous
//
#include <hip/hip_runtime.h>
#include <hip/hip_bf16.h>

typedef __hip_bfloat16 bf16;
typedef __attribute__((ext_vector_type(8))) short v8s;   // 8 bf16 raw (4 VGPRs)
typedef __attribute__((ext_vector_type(4))) short v4s;   // 4 bf16 raw (8 B)
typedef __attribute__((ext_vector_type(4))) float v4f;   // MFMA C/D frag

#define MFMA(a, b, c) __builtin_amdgcn_mfma_f32_16x16x32_bf16((a), (b), (c), 0, 0, 0)

static constexpr int BB = 2, SEQ = 4096, HIDN = 2048, NH = 16, NKV = 4, HD = 128;
static constexpr float SCALE = 0.08838834764831845f;  // 128^-0.5
static constexpr float NEGV = -1e9f;

__device__ __forceinline__ bf16 f2b(float x) { return __float2bfloat16(x); }

// async global->LDS, 16B per lane. ldst wave-uniform; lane i lands at ldst+i*16.
__device__ __forceinline__ void glds16(const bf16* g, bf16* l) {
  __builtin_amdgcn_global_load_lds(
      (const __attribute__((address_space(1))) unsigned int*)g,
      (__attribute__((address_space(3))) unsigned int*)l, 16, 0, 0);
}

// ---------------------------------------------------------------- fp32 -> bf16
// vectorized: float4 in, 4x bf16 (8 B) out per thread. n must be %4 == 0.
__global__ void convert_k(const float* __restrict__ X, bf16* __restrict__ Y, long n) {
  long i4 = ((long)blockIdx.x * 256 + threadIdx.x) * 4;
  if (i4 >= n) return;
  v4f x = *(const v4f*)(X + i4);
  bf16 t[4];
#pragma unroll
  for (int j = 0; j < 4; j++) t[j] = f2b(x[j]);
  *(v4s*)(Y + i4) = *(const v4s*)t;
}

// ---------------------------------------------------------------- transpose+cast
// 64x64 LDS tile; coalesced f32 reads (256 B/wave) and bf16 writes (128 B/wave).
// Wt[n*K+k] = W[k*N+n]. Requires K,N multiples of 64.  (round-3 validated)
__global__ __launch_bounds__(256) void transpose_k(const float* __restrict__ W,
                                                   bf16* __restrict__ Wt,
                                                   int K, int N) {
  __shared__ bf16 tile[64][65];
  const int tx = threadIdx.x & 63, ty = threadIdx.x >> 6;  // 64 x 4
  const int k0 = blockIdx.y << 6, n0 = blockIdx.x << 6;
#pragma unroll
  for (int rr = 0; rr < 64; rr += 4)
    tile[tx][rr + ty] = f2b(W[(long)(k0 + rr + ty) * N + n0 + tx]);
  __syncthreads();
#pragma unroll
  for (int rr = 0; rr < 64; rr += 4)
    Wt[(long)(n0 + rr + ty) * K + k0 + tx] = tile[rr + ty][tx];
}

// ---------------------------------------------------------------- GEMM (B^T)
// 2-deep pipeline (T3 minimum) + XCD swizzle (T1) -- round-8 validated
// (big GEMMs dropped out of the top-5, total -38 us). Unchanged this round.
template <int MODE, typename OT>
__global__ __launch_bounds__(256) void gemm128(const bf16* __restrict__ A,
                                               const bf16* __restrict__ Bt,
                                               OT* __restrict__ C,
                                               int M, int N, int K) {
  __shared__ __align__(16) bf16 As[2][128 * 32];
  __shared__ __align__(16) bf16 Bs[2][128 * 32];

  const int tid = threadIdx.x;
  const int lane = tid & 63, wv = tid >> 6;
  const int wr = wv >> 1, wc = wv & 1;
  const int l15 = lane & 15, quad = lane >> 4;

  const int nwg = gridDim.x * gridDim.y;
  int bid = blockIdx.y * gridDim.x + blockIdx.x;
  bid = (bid & 7) * (nwg >> 3) + (bid >> 3);
  const int m0 = (bid / gridDim.x) * 128, n0 = (bid % gridDim.x) * 128;

  const bf16* aSrc = A + (long)(m0 + (tid >> 2)) * K + (tid & 3) * 8;
  const bf16* bSrc = Bt + (long)(n0 + (tid >> 2)) * K + (tid & 3) * 8;
  const long rowStride = (long)64 * K;

  int aoff[4], boff[4];
#pragma unroll
  for (int t = 0; t < 4; t++) {
    aoff[t] = (wr * 64 + t * 16 + l15) * 32 + quad * 8;
    boff[t] = (wc * 64 + t * 16 + l15) * 32 + quad * 8;
  }

  v4f acc[4][4];
#pragma unroll
  for (int i = 0; i < 4; i++)
#pragma unroll
    for (int j = 0; j < 4; j++) acc[i][j] = {0.f, 0.f, 0.f, 0.f};

  const int nIter = K >> 5;

  // prologue: stage tile 0
  {
    bf16* aD = As[0] + wv * 512;
    bf16* bD = Bs[0] + wv * 512;
    glds16(aSrc, aD);
    glds16(aSrc + rowStride, aD + 2048);
    glds16(bSrc, bD);
    glds16(bSrc + rowStride, bD + 2048);
    asm volatile("s_waitcnt vmcnt(0)" ::: "memory");
    __syncthreads();
  }

  for (int it = 0; it < nIter; ++it) {
    const int bsel = it & 1;
    if (it + 1 < nIter) {
      const int kc = (it + 1) << 5;
      bf16* aD = As[bsel ^ 1] + wv * 512;
      bf16* bD = Bs[bsel ^ 1] + wv * 512;
      glds16(aSrc + kc, aD);
      glds16(aSrc + rowStride + kc, aD + 2048);
      glds16(bSrc + kc, bD);
      glds16(bSrc + rowStride + kc, bD + 2048);
    }

    const bf16* Ab = As[bsel];
    const bf16* Bb = Bs[bsel];
    v8s af[4], bfv[4];
#pragma unroll
    for (int t = 0; t < 4; t++) {
      af[t] = *(const v8s*)(Ab + aoff[t]);
      bfv[t] = *(const v8s*)(Bb + boff[t]);
    }
#pragma unroll
    for (int i = 0; i < 4; i++)
#pragma unroll
      for (int j = 0; j < 4; j++) acc[i][j] = MFMA(af[i], bfv[j], acc[i][j]);

    // drain next-tile DMA (mostly landed during MFMA) + cross-wave sync
    asm volatile("s_waitcnt vmcnt(0)" ::: "memory");
    __syncthreads();
  }

#pragma unroll
  for (int i = 0; i < 4; i++)
#pragma unroll
    for (int j = 0; j < 4; j++)
#pragma unroll
      for (int r = 0; r < 4; r++) {
        int m = m0 + wr * 64 + i * 16 + quad * 4 + r;
        int n = n0 + wc * 64 + j * 16 + l15;
        long addr;
        if (MODE == 0) {
          addr = (long)m * N + n;
        } else {
          int bb = m >> 12, s = m & (SEQ - 1);
          int hh = n >> 7, d = n & (HD - 1);
          if (MODE == 1)      addr = ((long)(bb * NH + hh) * SEQ + s) * HD + d;
          else if (MODE == 2) addr = ((long)(bb * NKV + hh) * SEQ + s) * HD + d;
          else                addr = ((long)(bb * NKV + hh) * HD + d) * SEQ + s;
        }
        float v = acc[i][j][r];
        if constexpr (sizeof(OT) == 2) C[addr] = f2b(v);
        else                           C[addr] = v;
      }
}

// ---------------------------------------------------------------- RoPE (in place)
__global__ void rope_k(bf16* __restrict__ X, const float* __restrict__ cs,
                       const float* __restrict__ sn, int nheads) {
  int idx = blockIdx.x * 256 + threadIdx.x;
  int d = idx & 63;
  int row = idx >> 6;
  int s = row & (SEQ - 1);
  int bh = row >> 12;
  int b = bh / nheads;
  long xo = (long)row * HD;
  long co = ((long)b * SEQ + s) * HD;
  float x1 = __bfloat162float(X[xo + d]), x2 = __bfloat162float(X[xo + d + 64]);
  float c1 = cs[co + d], c2 = cs[co + d + 64];
  float s1 = sn[co + d], s2 = sn[co + d + 64];
  X[xo + d] = f2b(x1 * c1 - x2 * s1);
  X[xo + d + 64] = f2b(x2 * c2 + x1 * s2);
}

// ---------------------------------------------------------------- attention
// Round-9 change: __launch_bounds__(1024, 4). Round-8 counters caught a spill:
// VGPR_Count=64 (compiler defaulted to an 8-waves/EU register budget for the
// 1024-thread block) vs ~104 live VGPRs -> WRITE_SIZE 161.8 MB (128 MB scratch
// writes) + FETCH 129 MB (spill re-reads). LDS=100KB forces 1 block/CU = 16
// waves = 4 waves/SIMD, so declaring min 4 waves/EU raises the VGPR cap to
// 512/4 = 128 -- fits the ~104-VGPR live set with zero spill (round-6 measured
// 104 for the same per-wave code). Everything else bit-identical to round 8.
__global__ __launch_bounds__(1024, 4) void attn_k(const bf16* __restrict__ Q,
                                                  const bf16* __restrict__ K,
                                                  const bf16* __restrict__ V,
                                                  const float* __restrict__ msk,
                                                  bf16* __restrict__ ctx) {
  const int i = blockIdx.x;                       // qblock
  const int kv = blockIdx.y, b = blockIdx.z;
  const int lane = threadIdx.x & 63, wv = threadIdx.x >> 6;  // 16 waves
  const int j = wv >> 2;                          // 16-row slice 0..3
  const int h = kv * 4 + (wv & 3);                // this wave's q-head
  const int l15 = lane & 15, quad = lane >> 4;

  __shared__ __align__(16) bf16 kbuf[2][8192];   // K block: 64 tok x 128 d
  __shared__ __align__(16) bf16 vbuf[2][8192];   // V block: 128 d x 64 tok
  __shared__ __align__(16) bf16 pb[16][16][72];  // per-wave P transpose

  // key-block table: kb[0..3] local (kb[3]==i self), kb[4..7] strided global
  int kb[8];
  bool kval[8];
#pragma unroll
  for (int w = 0; w < 4; w++) { kb[w] = i - 3 + w; kval[w] = (kb[w] >= 0); }
  {
    int st = i - 32; if (st < 0) st = 0;
    int n = i - st;
    int cnt = (n + 3) >> 2;
#pragma unroll
    for (int t = 0; t < 4; t++) {
      int jj = cnt + t - 4;
      kval[4 + t] = (jj >= 0);
      kb[4 + t] = (jj >= 0) ? (st + 4 * jj) : 0;
    }
  }
  int kbc[8];
#pragma unroll
  for (int t = 0; t < 8; t++) kbc[t] = kb[t] < 0 ? 0 : kb[t];  // clamped for staging

  // Q fragments: this wave's 16 q-rows
  const bf16* qp = Q + ((long)(b * NH + h) * SEQ + i * 64 + j * 16 + l15) * HD + quad * 8;
  v8s qf[4];
#pragma unroll
  for (int kk = 0; kk < 4; kk++) qf[kk] = *(const v8s*)(qp + kk * 32);

  // staging lane geometry (K): 4 rows/call (64 rows / 16 waves), 16B granules
  const int klr = lane >> 4, kgp = lane & 15;
  // staging lane geometry (V): 8 rows/call (128 rows / 16 waves)
  const int vlr = lane >> 3, vgp = lane & 7;

  const bf16* gk = K + (long)(b * NKV + kv) * SEQ * HD;
  const bf16* gv = V + (long)(b * NKV + kv) * HD * SEQ;

  // stage K block blk: LDS[row][g'] = K[row][g' ^ (row&15)]; wave wv stages
  // token rows wv*4 .. wv*4+3 in ONE glds16 (64 lanes x 16B = 4 rows x 256B)
  auto stageK = [&](int blk, bf16* dst) {
    const bf16* kbase = gk + (long)blk * 64 * HD;
    int tl = wv * 4 + klr;                        // token row 0..63
    int g = kgp ^ (tl & 15);
    glds16(kbase + (long)tl * HD + g * 8, dst + (wv * 4) * 128);
  };
  // stage V block blk: LDS[row][g'] = V[row][g' ^ (row&7)]; wave wv stages
  // d rows wv*8 .. wv*8+7 in ONE glds16 (64 lanes x 16B = 8 rows x 128B)
  auto stageV = [&](int blk, bf16* dst) {
    const bf16* vbase = gv + (long)blk * 64;      // token offset within d-rows
    int row = wv * 8 + vlr;                       // d row 0..127
    int g = vgp ^ (row & 7);
    glds16(vbase + (long)row * SEQ + g * 8, dst + (wv * 8) * 64);
  };

  float rsum[4] = {0.f, 0.f, 0.f, 0.f};
  v4f oacc[8] = {{0.f, 0.f, 0.f, 0.f}, {0.f, 0.f, 0.f, 0.f}, {0.f, 0.f, 0.f, 0.f},
                 {0.f, 0.f, 0.f, 0.f}, {0.f, 0.f, 0.f, 0.f}, {0.f, 0.f, 0.f, 0.f},
                 {0.f, 0.f, 0.f, 0.f}, {0.f, 0.f, 0.f, 0.f}};

  stageK(kbc[0], kbuf[0]);
  stageV(kbc[0], vbuf[0]);
  asm volatile("s_waitcnt vmcnt(0)" ::: "memory");
  __syncthreads();

#pragma unroll
  for (int it = 0; it < 8; ++it) {
    const int bsel = it & 1;
    if (it < 7) {
      stageK(kbc[it + 1], kbuf[bsel ^ 1]);
      stageV(kbc[it + 1], vbuf[bsel ^ 1]);
    }

    // ---- QK^T -> exp -> pb, fused per t (exp of tile t overlaps MFMA of t+1)
    const bf16* Kb = kbuf[bsel];
    __builtin_amdgcn_s_setprio(1);
#pragma unroll
    for (int t = 0; t < 4; t++) {
      v4f acc = {0.f, 0.f, 0.f, 0.f};
#pragma unroll
      for (int kk = 0; kk < 4; kk++) {
        int off = (t * 16 + l15) * 128 + (((kk * 4 + quad) ^ l15) * 8);
        acc = MFMA(qf[kk], *(const v8s*)(Kb + off), acc);
      }
      int tokc = kbc[it] * 64 + t * 16 + l15;
      float madd = kval[it] ? (1.0f - msk[b * SEQ + tokc]) * NEGV : NEGV;
#pragma unroll
      for (int r = 0; r < 4; r++) {
        float x = acc[r] * SCALE + madd;
        if (it == 3) {  // self block: causal within block
          int kpp = t * 16 + l15;
          int qpp = j * 16 + quad * 4 + r;
          if (kpp > qpp) x += NEGV;
        }
        float e = __expf(x);   // masked -> exp(~-1e9) = 0 exactly
        rsum[r] += e;
        pb[wv][quad * 4 + r][t * 16 + l15] = f2b(e);
      }
    }
    __builtin_amdgcn_s_setprio(0);

    // ---- PV accumulate (pb write->read ordered by lgkmcnt within the wave)
    const bf16* Vb = vbuf[bsel];
    __builtin_amdgcn_s_setprio(1);
#pragma unroll
    for (int hf = 0; hf < 2; hf++) {
      v8s af = *(const v8s*)&pb[wv][l15][hf * 32 + quad * 8];
#pragma unroll
      for (int nt = 0; nt < 8; nt++) {
        int off = (nt * 16 + l15) * 64 + (((hf * 4 + quad) ^ (l15 & 7)) * 8);
        oacc[nt] = MFMA(af, *(const v8s*)(Vb + off), oacc[nt]);
      }
    }
    __builtin_amdgcn_s_setprio(0);
    // single per-iteration barrier; drains the it+1 DMA (vmcnt(0) before
    // s_barrier) and separates this iteration's LDS reads from it+1 writes
    __syncthreads();
  }

  // ---- final sum reduce across the 16 column-lanes (once, outside the loop)
#pragma unroll
  for (int m = 1; m <= 8; m <<= 1)
#pragma unroll
    for (int r = 0; r < 4; r++) rsum[r] += __shfl_xor(rsum[r], m, 64);

  // ---- normalize + write ctx[b][s][h*128+d]
  const int tokw = i * 64 + j * 16 + quad * 4;
#pragma unroll
  for (int nt = 0; nt < 8; nt++)
#pragma unroll
    for (int r = 0; r < 4; r++) {
      float v = oacc[nt][r] / rsum[r];
      long addr = ((long)b * SEQ + tokw + r) * (NH * HD) + h * HD + nt * 16 + l15;
      ctx[addr] = f2b(v);
    }
}

// ---------------------------------------------------------------- launch
extern "C" void kernel_launch(void* const* d_in, const int* in_sizes, int n_in,
                              void* d_out, int out_size, void* d_ws, size_t ws_size,
                              hipStream_t stream) {
  const float* hs  = (const float*)d_in[0];
  const float* cs  = (const float*)d_in[1];
  const float* sn  = (const float*)d_in[2];
  const float* msk = (const float*)d_in[3];
  const float* Wq  = (const float*)d_in[4];
  const float* Wk  = (const float*)d_in[5];
  const float* Wv  = (const float*)d_in[6];
  const float* Wo  = (const float*)d_in[7];
  float* out = (float*)d_out;

  char* w = (char*)d_ws;
  bf16* hsb = (bf16*)w; w += (size_t)BB * SEQ * HIDN * 2;       // 33.5 MB
  bf16* Wqt = (bf16*)w; w += (size_t)2048 * 2048 * 2;           //  8.4 MB
  bf16* Wkt = (bf16*)w; w += (size_t)512 * 2048 * 2;            //  2.1 MB
  bf16* Wvt = (bf16*)w; w += (size_t)512 * 2048 * 2;            //  2.1 MB
  bf16* Wot = (bf16*)w; w += (size_t)2048 * 2048 * 2;           //  8.4 MB
  bf16* Qr  = (bf16*)w; w += (size_t)BB * NH * SEQ * HD * 2;    // 33.5 MB
  bf16* Kr  = (bf16*)w; w += (size_t)BB * NKV * SEQ * HD * 2;   //  8.4 MB
  bf16* Vt  = (bf16*)w; w += (size_t)BB * NKV * HD * SEQ * 2;   //  8.4 MB
  bf16* ctx = hsb;  // hsb dead after V-proj; stream-ordered reuse
  // total ws use: ~105 MB

  long nhs = (long)BB * SEQ * HIDN;
  convert_k<<<(int)(nhs / 4 / 256), 256, 0, stream>>>(hs, hsb, nhs);

  transpose_k<<<dim3(2048 / 64, 2048 / 64), 256, 0, stream>>>(Wq, Wqt, 2048, 2048);
  transpose_k<<<dim3(512 / 64, 2048 / 64), 256, 0, stream>>>(Wk, Wkt, 2048, 512);
  transpose_k<<<dim3(512 / 64, 2048 / 64), 256, 0, stream>>>(Wv, Wvt, 2048, 512);
  transpose_k<<<dim3(2048 / 64, 2048 / 64), 256, 0, stream>>>(Wo, Wot, 2048, 2048);

  gemm128<1, bf16><<<dim3(2048 / 128, 8192 / 128), 256, 0, stream>>>(hsb, Wqt, Qr, 8192, 2048, 2048);
  gemm128<2, bf16><<<dim3(512 / 128, 8192 / 128), 256, 0, stream>>>(hsb, Wkt, Kr, 8192, 512, 2048);
  gemm128<3, bf16><<<dim3(512 / 128, 8192 / 128), 256, 0, stream>>>(hsb, Wvt, Vt, 8192, 512, 2048);

  rope_k<<<(BB * NH * SEQ * 64) / 256, 256, 0, stream>>>(Qr, cs, sn, NH);
  rope_k<<<(BB * NKV * SEQ * 64) / 256, 256, 0, stream>>>(Kr, cs, sn, NKV);

  attn_k<<<dim3(64, 4, 2), 1024, 0, stream>>>(Qr, Kr, Vt, msk, ctx);

  gemm128<0, float><<<dim3(2048 / 128, 8192 / 128), 256, 0, stream>>>(ctx, Wot, out, 8192, 2048, 2048);
}